// Round 5
// baseline (991.125 us; speedup 1.0000x reference)
//
#include <hip/hip_runtime.h>
#include <math.h>
#include <stdint.h>

#define DEV static __device__ __forceinline__
typedef unsigned short u16;

constexpr int D = 256;
constexpr int S = 4096;
constexpr int QSTR = 272;            // Qb row: 256 data + 12 bias-ext + 4 zero
constexpr int KT_TILE = 8960;        // u16: 32 rows x 280
constexpr int VT_TILE = 10240;       // u16: 256 rows x 40

typedef short bf16x8 __attribute__((ext_vector_type(8)));
typedef float f32x16 __attribute__((ext_vector_type(16)));

DEV u16 f2bf(float f){ unsigned u = __float_as_uint(f); return (u16)((u + 0x7fffu + ((u>>16)&1u)) >> 16); }
DEV float bf2f(u16 h){ return __uint_as_float(((unsigned)h)<<16); }
DEV int packbf(float lo, float hi){ return (int)((((unsigned)f2bf(hi)) << 16) | (unsigned)f2bf(lo)); }
DEV float bfsum2(int d){
  return __uint_as_float(((unsigned)d)<<16) + __uint_as_float(((unsigned)d) & 0xffff0000u);
}
DEV void gl_lds16(const u16* g, u16* l) {
  __builtin_amdgcn_global_load_lds(
      (const __attribute__((address_space(1))) unsigned int*)g,
      (__attribute__((address_space(3))) unsigned int*)l, 16, 0, 0);
}

// ---------------- prep: hi/lo split (interleaved layouts), bias-ext cols, zero out/Lacc -----
__global__ __launch_bounds__(256) void msp_prep(
    const float* __restrict__ x, const float* __restrict__ Wq,
    const float* __restrict__ Wk, const float* __restrict__ Wv,
    const float* __restrict__ beta,
    u16* __restrict__ xc, u16* __restrict__ Wc,
    u16* __restrict__ Qb, u16* __restrict__ Kt,
    float* __restrict__ out, float* __restrict__ Lacc)
{
  const int blk = blockIdx.x, tid = threadIdx.x;
  if (blk < 2048) {                       // xc[row][0..255]=hi, [256..511]=lo
    int row = blk*8 + (tid>>5);
    int col = (tid&31)*8;
    const float* p = x + (size_t)row*256 + col;
    union { u16 s[8]; uint4 v; } hh, ll;
    #pragma unroll
    for (int i=0;i<8;++i){ float v = p[i]; u16 h2 = f2bf(v); hh.s[i]=h2; ll.s[i]=f2bf(v - bf2f(h2)); }
    *(uint4*)(xc + (size_t)row*512 + col)       = hh.v;
    *(uint4*)(xc + (size_t)row*512 + 256 + col) = ll.v;
  } else if (blk < 2144) {                // Wc rows: [0,256)=Wq/16, [256,512)=Wk, [512,768)=Wv
    int q = blk - 2048;                   // 96 blocks
    int mat = q >> 5;
    int idx = (q & 31)*2048 + tid*8;      // 0..65535
    int o = idx >> 8, cc = idx & 255;
    const float* W = mat==0 ? Wq : (mat==1 ? Wk : Wv);
    float sc = (mat==0) ? 0.0625f : 1.0f;
    const float* p = W + (size_t)o*256 + cc;
    union { u16 s[8]; uint4 v; } hh, ll;
    #pragma unroll
    for (int i=0;i<8;++i){ float v = p[i]*sc; u16 h2 = f2bf(v); hh.s[i]=h2; ll.s[i]=f2bf(v - bf2f(h2)); }
    *(uint4*)(Wc + (size_t)(mat*256 + o)*512 + cc)       = hh.v;
    *(uint4*)(Wc + (size_t)(mat*256 + o)*512 + 256 + cc) = ll.v;
  } else if (blk < 2208) {                // bias-ext cols (64 blocks)
    int row = (blk - 2208 + 64)*256 + tid;  // b*4096 + s
    int s = row & (S-1);
    int bb = row >> 12;
    float b0 = beta[0], b1 = beta[1];
    int i24 = s % 24, i720 = s % 720;
    float t0 = (float)i24  * 0.26179938779914944f;    // 2pi/24
    float t1 = (float)i720 * 0.008726646259971648f;   // 2pi/720
    float c0 = cosf(t0), s0 = sinf(t0), c1 = cosf(t1), s1 = sinf(t1);
    float qv[4] = {b0*c0, b0*s0, b1*c1, b1*s1};   // beta folded on Q side
    float kv[4] = {c0, s0, c1, s1};
    u16* qp = Qb + (size_t)row*QSTR + 256;
    u16* kp = Kt + (size_t)(bb*128 + (s>>5))*KT_TILE + (s&31)*280 + 256;
    #pragma unroll
    for (int n=0;n<4;++n){
      u16 uh = f2bf(qv[n]); u16 ul = f2bf(qv[n]-bf2f(uh));
      u16 vh = f2bf(kv[n]); u16 vl = f2bf(kv[n]-bf2f(vh));
      // dot over triplet = uh*vh + uh*vl + ul*vh ~= u*v (drops ul*vl <= 2^-18)
      qp[n*3+0]=uh; qp[n*3+1]=uh; qp[n*3+2]=ul;
      kp[n*3+0]=vh; kp[n*3+1]=vl; kp[n*3+2]=vh;
    }
    #pragma unroll
    for (int c=12;c<16;++c){ qp[c]=0; kp[c]=0; }
  } else if (blk < 3232) {                // zero out (16.8 MB)
    float4* p = (float4*)(out + (size_t)(blk-2208)*4096);
    float4 z = {0.f,0.f,0.f,0.f};
    #pragma unroll
    for (int c=0;c<4;++c) p[tid + c*256] = z;
  } else {                                // zero Lacc (16384 f32)
    float4* p = (float4*)Lacc;
    float4 z = {0.f,0.f,0.f,0.f};
    #pragma unroll
    for (int c=0;c<16;++c) p[tid + c*256] = z;
  }
}

// ---------------- fused projection GEMM: C[16384x768] = xc . Wc^T, route Q/K/V ----------------
__global__ __launch_bounds__(256, 2) void msp_proj(
    const u16* __restrict__ xc, const u16* __restrict__ Wc,
    const float* __restrict__ bq, const float* __restrict__ bk, const float* __restrict__ bv,
    u16* __restrict__ Qb, u16* __restrict__ Kt, u16* __restrict__ Vt)
{
  __shared__ __align__(16) u16 smem[2][2][128][72];   // [buf][A/B][row][64+8pad] = 73728 B

  const int tid = threadIdx.x;
  const int w = tid >> 6, lane = tid & 63;
  const int l31 = lane & 31, h = lane >> 5;
  const int m0 = blockIdx.x * 128;
  const int nblk = blockIdx.y;
  const int n0 = nblk * 128, mat = nblk >> 1, cb = (nblk & 1) * 128;
  const int mh = (w & 1) * 64, nh = (w >> 1) * 64;

  const int srow = tid & 127;
  const int isB = tid >> 7;
  const u16* sgbase = isB ? (Wc + (size_t)(n0 + srow)*512) : (xc + (size_t)(m0 + srow)*512);

  { // prologue: chunk 0 -> buf 0
    u16* d = &smem[0][isB][srow][0];
    #pragma unroll
    for (int jj=0; jj<8; ++jj) *(uint4*)(d + jj*8) = *(const uint4*)(sgbase + jj*8);
  }

  f32x16 acc[2][2];
  #pragma unroll
  for (int a=0;a<2;++a)
    #pragma unroll
    for (int c=0;c<2;++c)
      #pragma unroll
      for (int i=0;i<16;++i) acc[a][c][i] = 0.f;

  for (int kc8 = 0; kc8 < 8; ++kc8) {
    __syncthreads();
    const int p = kc8 & 1;
    uint4 nxt[8];
    if (kc8 < 7) {
      const u16* g = sgbase + (kc8+1)*64;
      #pragma unroll
      for (int jj=0; jj<8; ++jj) nxt[jj] = *(const uint4*)(g + jj*8);
    }
    #pragma unroll
    for (int kf = 0; kf < 4; ++kf) {
      const int ko = kf*16 + h*8;
      bf16x8 a0 = *(const bf16x8*)&smem[p][0][mh + l31][ko];
      bf16x8 a1 = *(const bf16x8*)&smem[p][0][mh + 32 + l31][ko];
      bf16x8 b0 = *(const bf16x8*)&smem[p][1][nh + l31][ko];
      bf16x8 b1 = *(const bf16x8*)&smem[p][1][nh + 32 + l31][ko];
      acc[0][0] = __builtin_amdgcn_mfma_f32_32x32x16_bf16(a0, b0, acc[0][0], 0,0,0);
      acc[0][1] = __builtin_amdgcn_mfma_f32_32x32x16_bf16(a0, b1, acc[0][1], 0,0,0);
      acc[1][0] = __builtin_amdgcn_mfma_f32_32x32x16_bf16(a1, b0, acc[1][0], 0,0,0);
      acc[1][1] = __builtin_amdgcn_mfma_f32_32x32x16_bf16(a1, b1, acc[1][1], 0,0,0);
    }
    if (kc8 < 7) {
      u16* d = &smem[p^1][isB][srow][0];
      #pragma unroll
      for (int jj=0; jj<8; ++jj) *(uint4*)(d + jj*8) = nxt[jj];
    }
  }

  const float* bias = mat==0 ? bq : (mat==1 ? bk : bv);
  const float bsc = (mat==0) ? 0.0625f : 1.0f;   // W was pre-scaled; bias scaled here
  float bb_[2];
  #pragma unroll
  for (int ntl=0; ntl<2; ++ntl) bb_[ntl] = bias[cb + nh + ntl*32 + l31] * bsc;

  if (mat <= 1) {
    #pragma unroll
    for (int mt=0; mt<2; ++mt)
      #pragma unroll
      for (int ntl=0; ntl<2; ++ntl)
        #pragma unroll
        for (int r=0; r<16; ++r) {
          int gm = m0 + mh + mt*32 + (r&3) + 8*(r>>2) + 4*h;
          int col = cb + nh + ntl*32 + l31;
          u16 val = f2bf(acc[mt][ntl][r] + bb_[ntl]);
          if (mat == 0) {
            Qb[(size_t)gm*QSTR + col] = val;
          } else {
            int bb2 = gm >> 12, s = gm & (S-1);
            Kt[(size_t)(bb2*128 + (s>>5))*KT_TILE + (s&31)*280 + col] = val;
          }
        }
  } else {
    // V: transpose via LDS, store to Vt tiled [b][t32][e][40]
    u16* T = (u16*)smem;     // [128 e][136]
    #pragma unroll
    for (int mt=0; mt<2; ++mt)
      #pragma unroll
      for (int ntl=0; ntl<2; ++ntl)
        #pragma unroll
        for (int r=0; r<16; ++r) {
          int e_loc = nh + ntl*32 + l31;
          int m_loc = mh + mt*32 + (r&3) + 8*(r>>2) + 4*h;
          T[(size_t)e_loc*136 + m_loc] = f2bf(acc[mt][ntl][r] + bb_[ntl]);
        }
    __syncthreads();
    int e_loc = tid >> 1, shalf = (tid & 1)*64;
    int e = cb + e_loc;
    #pragma unroll
    for (int g2 = 0; g2 < 2; ++g2) {
      int gm = m0 + shalf + g2*32;
      int bb2 = gm >> 12, s = gm & (S-1);
      u16* dst = Vt + (size_t)(bb2*128 + (s>>5))*VT_TILE + (size_t)e*40;
      const u16* src = T + (size_t)e_loc*136 + shalf + g2*32;
      #pragma unroll
      for (int k2=0;k2<4;++k2) *(uint4*)(dst + k2*8) = *(const uint4*)(src + k2*8);
    }
  }
}

// ---------------- attention: BK=32, async dbuf, 2 blocks/CU, t-split partials via atomics ----
__global__ __launch_bounds__(256, 2) void msp_attn(
    const u16* __restrict__ Qb, const u16* __restrict__ Kt,
    const u16* __restrict__ Vt, float* __restrict__ out,
    float* __restrict__ Lacc)
{
  __shared__ __align__(16) unsigned char smem[77824];  // K dbuf 2x18432 | V dbuf 2x20480

  const int tid = threadIdx.x;
  const int w = tid >> 6, lane = tid & 63;
  const int l31 = lane & 31, h = lane >> 5;

  // XCD-swizzled decode over 512 blocks: 32 qt-blocks sharing (b,tq) land on one XCD
  const int xg = blockIdx.x;
  const int xcd = xg & 7, j = xg >> 3;
  const int c = xcd*2 + (j & 1);
  const int qt = j >> 1;
  const int b = c >> 2, tq = c & 3;
  const int q0 = qt * 128;
  const int qw = q0 + w*32;

  // Q fragments (B-operand): lane holds Q[qw+l31][16*s2 + 8h + j]
  bf16x8 qf[17];
  {
    const u16* qp = Qb + ((size_t)b*S + qw + l31)*QSTR + h*8;
    #pragma unroll
    for (int s2=0; s2<17; ++s2) qf[s2] = *(const bf16x8*)(qp + s2*16);
  }

  const int tIdx0 = b*128 + tq*32;

  f32x16 oacc[8];
  #pragma unroll
  for (int e=0;e<8;++e)
    #pragma unroll
    for (int i=0;i<16;++i) oacc[e][i] = 0.f;
  float l_acc = 0.f;

  { // prologue: tile 0 -> buffer 0
    const u16* kg = Kt + (size_t)tIdx0*KT_TILE;
    u16* kl = (u16*)smem;
    #pragma unroll
    for (int i = w; i < 18; i += 4) gl_lds16(kg + i*512 + lane*8, kl + i*512);
    const u16* vg = Vt + (size_t)tIdx0*VT_TILE;
    u16* vl = (u16*)(smem + 36864);
    #pragma unroll
    for (int i = w; i < 20; i += 4) gl_lds16(vg + i*512 + lane*8, vl + i*512);
  }

  for (int it = 0; it < 32; ++it) {
    __syncthreads();            // buf[it&1] staged; previous buf's readers drained
    const int p = it & 1;
    if (it < 31) {              // async-stage next tile into the other buffer
      const u16* kg = Kt + (size_t)(tIdx0 + it + 1)*KT_TILE;
      u16* kl = (u16*)(smem + (p^1)*18432);
      #pragma unroll
      for (int i = w; i < 18; i += 4) gl_lds16(kg + i*512 + lane*8, kl + i*512);
      const u16* vg = Vt + (size_t)(tIdx0 + it + 1)*VT_TILE;
      u16* vl = (u16*)(smem + 36864 + (p^1)*20480);
      #pragma unroll
      for (int i = w; i < 20; i += 4) gl_lds16(vg + i*512 + lane*8, vl + i*512);
    }

    // S^T = K Q^T (scale + periodic bias folded into the 272-dim), 2 chains
    const u16* Kp = (const u16*)(smem + p*18432) + (size_t)l31*280 + h*8;
    f32x16 sa, sb;
    #pragma unroll
    for (int i=0;i<16;++i){ sa[i] = 0.f; sb[i] = 0.f; }
    #pragma unroll
    for (int s2 = 0; s2 < 17; ++s2) {
      bf16x8 kf = *(const bf16x8*)(Kp + s2*16);
      if (s2 & 1) sb = __builtin_amdgcn_mfma_f32_32x32x16_bf16(kf, qf[s2], sb, 0,0,0);
      else        sa = __builtin_amdgcn_mfma_f32_32x32x16_bf16(kf, qf[s2], sa, 0,0,0);
    }
    f32x16 sc = sa + sb;

    // p = exp(s) (scores bounded ~|9|); build P^T B-frags via xor-32 exchange
    bf16x8 pf[2];
    #pragma unroll
    for (int s2 = 0; s2 < 2; ++s2) {
      float e0 = __expf(sc[8*s2+0]), e1 = __expf(sc[8*s2+1]);
      float e2 = __expf(sc[8*s2+2]), e3 = __expf(sc[8*s2+3]);
      float e4 = __expf(sc[8*s2+4]), e5 = __expf(sc[8*s2+5]);
      float e6 = __expf(sc[8*s2+6]), e7 = __expf(sc[8*s2+7]);
      int P0d0 = packbf(e0, e1), P0d1 = packbf(e2, e3);
      int P1d0 = packbf(e4, e5), P1d1 = packbf(e6, e7);
      // l sums the bf16-ROUNDED p so normalization cancels rounding bias
      l_acc += bfsum2(P0d0) + bfsum2(P0d1) + bfsum2(P1d0) + bfsum2(P1d1);
      int s0 = h ? P0d0 : P1d0;
      int s1 = h ? P0d1 : P1d1;
      int r0 = __shfl_xor(s0, 32, 64);
      int r1 = __shfl_xor(s1, 32, 64);
      union { int d[4]; bf16x8 v; } u;
      u.d[0] = h ? r0 : P0d0;
      u.d[1] = h ? r1 : P0d1;
      u.d[2] = h ? P1d0 : r0;
      u.d[3] = h ? P1d1 : r1;
      pf[s2] = u.v;
    }

    // O^T += V^T P^T
    const u16* Vp = (const u16*)(smem + 36864 + p*20480) + (size_t)l31*40 + h*8;
    #pragma unroll
    for (int et = 0; et < 8; ++et) {
      const u16* vb = Vp + et*32*40;
      oacc[et] = __builtin_amdgcn_mfma_f32_32x32x16_bf16(*(const bf16x8*)(vb),      pf[0], oacc[et], 0,0,0);
      oacc[et] = __builtin_amdgcn_mfma_f32_32x32x16_bf16(*(const bf16x8*)(vb + 16), pf[1], oacc[et], 0,0,0);
    }
  }

  // l: fold h-halves, one atomic per q-row
  float l_tot = l_acc + __shfl_xor(l_acc, 32, 64);
  if (h == 0) unsafeAtomicAdd(&Lacc[(size_t)b*S + qw + l31], l_tot);

  // transpose O^T -> O via LDS (4 rounds, one wave each), coalesced fp32 atomics into out
  float* Ofl = (float*)smem;    // [32 q][260]
  for (int rnd = 0; rnd < 4; ++rnd) {
    __syncthreads();
    if (w == rnd) {
      #pragma unroll
      for (int et=0; et<8; ++et)
        #pragma unroll
        for (int g=0; g<4; ++g) {
          float4 v4 = { oacc[et][4*g+0], oacc[et][4*g+1], oacc[et][4*g+2], oacc[et][4*g+3] };
          *(float4*)&Ofl[(size_t)l31*260 + et*32 + 8*g + 4*h] = v4;
        }
    }
    __syncthreads();
    float* obase = out + ((size_t)b*S + q0 + rnd*32)*D;
    const int q = tid >> 3, ee0 = (tid & 7)*32;
    #pragma unroll
    for (int jj = 0; jj < 8; ++jj) {
      float4 v4 = *(const float4*)&Ofl[(size_t)q*260 + ee0 + jj*4];
      float* dp = obase + (size_t)q*D + ee0 + jj*4;
      unsafeAtomicAdd(dp + 0, v4.x);
      unsafeAtomicAdd(dp + 1, v4.y);
      unsafeAtomicAdd(dp + 2, v4.z);
      unsafeAtomicAdd(dp + 3, v4.w);
    }
  }
}

// ---------------- normalize ----------------
__global__ __launch_bounds__(256) void msp_norm(float* __restrict__ out, const float* __restrict__ L) {
  int idx = blockIdx.x*256 + threadIdx.x;
  int row = idx >> 6, e0 = (idx & 63)*4;
  float inv = 1.0f / L[row];
  float4* p = (float4*)(out + (size_t)row*256 + e0);
  float4 v = *p;
  v.x *= inv; v.y *= inv; v.z *= inv; v.w *= inv;
  *p = v;
}

extern "C" void kernel_launch(void* const* d_in, const int* in_sizes, int n_in,
                              void* d_out, int out_size, void* d_ws, size_t ws_size,
                              hipStream_t stream) {
  const float* x    = (const float*)d_in[0];
  const float* Wq   = (const float*)d_in[1];
  const float* bq   = (const float*)d_in[2];
  const float* Wk   = (const float*)d_in[3];
  const float* bk   = (const float*)d_in[4];
  const float* Wv   = (const float*)d_in[5];
  const float* bv   = (const float*)d_in[6];
  const float* beta = (const float*)d_in[7];
  float* out = (float*)d_out;

  char* w = (char*)d_ws;
  u16* xc = (u16*)w;  w += (size_t)16384*512*2;     // 16.8 MB
  u16* Wc = (u16*)w;  w += (size_t)768*512*2;       // 0.79 MB
  u16* Qb = (u16*)w;  w += (size_t)16384*QSTR*2;    // 8.9 MB
  u16* Kt = (u16*)w;  w += (size_t)512*KT_TILE*2;   // 9.2 MB (Vt must follow: junk-tail reads)
  u16* Vt = (u16*)w;  w += (size_t)512*VT_TILE*2;   // 10.5 MB
  float* Lacc = (float*)w;                          // 64 KB

  msp_prep<<<3233, 256, 0, stream>>>(x, Wq, Wk, Wv, beta, xc, Wc, Qb, Kt, out, Lacc);
  msp_proj<<<dim3(128, 6), 256, 0, stream>>>(xc, Wc, bq, bk, bv, Qb, Kt, Vt);
  msp_attn<<<512, 256, 0, stream>>>(Qb, Kt, Vt, out, Lacc);
  msp_norm<<<4096, 256, 0, stream>>>(out, Lacc);
}

// Round 6
// 247.417 us; speedup vs baseline: 4.0059x; 4.0059x over previous
//
#include <hip/hip_runtime.h>
#include <math.h>
#include <stdint.h>

#define DEV static __device__ __forceinline__
typedef unsigned short u16;

constexpr int D = 256;
constexpr int S = 4096;
constexpr int QSTR = 272;            // Qb row: 256 data + 12 bias-ext + 4 zero
constexpr int KT_TILE = 8960;        // u16: 32 rows x 280
constexpr int VT_TILE = 10240;       // u16: 256 rows x 40

typedef short bf16x8 __attribute__((ext_vector_type(8)));
typedef float f32x16 __attribute__((ext_vector_type(16)));

DEV u16 f2bf(float f){ unsigned u = __float_as_uint(f); return (u16)((u + 0x7fffu + ((u>>16)&1u)) >> 16); }
DEV float bf2f(u16 h){ return __uint_as_float(((unsigned)h)<<16); }
DEV int packbf(float lo, float hi){ return (int)((((unsigned)f2bf(hi)) << 16) | (unsigned)f2bf(lo)); }
DEV float bfsum2(int d){
  return __uint_as_float(((unsigned)d)<<16) + __uint_as_float(((unsigned)d) & 0xffff0000u);
}
DEV void gl_lds16(const u16* g, u16* l) {
  __builtin_amdgcn_global_load_lds(
      (const __attribute__((address_space(1))) unsigned int*)g,
      (__attribute__((address_space(3))) unsigned int*)l, 16, 0, 0);
}

// ---------------- prep: hi/lo split (interleaved layouts), bias-ext cols, zero out/Lacc -----
__global__ __launch_bounds__(256) void msp_prep(
    const float* __restrict__ x, const float* __restrict__ Wq,
    const float* __restrict__ Wk, const float* __restrict__ Wv,
    const float* __restrict__ beta,
    u16* __restrict__ xc, u16* __restrict__ Wc,
    u16* __restrict__ Qb, u16* __restrict__ Kt,
    float* __restrict__ out, float* __restrict__ Lacc)
{
  const int blk = blockIdx.x, tid = threadIdx.x;
  if (blk < 2048) {                       // xc[row][0..255]=hi, [256..511]=lo
    int row = blk*8 + (tid>>5);
    int col = (tid&31)*8;
    const float* p = x + (size_t)row*256 + col;
    union { u16 s[8]; uint4 v; } hh, ll;
    #pragma unroll
    for (int i=0;i<8;++i){ float v = p[i]; u16 h2 = f2bf(v); hh.s[i]=h2; ll.s[i]=f2bf(v - bf2f(h2)); }
    *(uint4*)(xc + (size_t)row*512 + col)       = hh.v;
    *(uint4*)(xc + (size_t)row*512 + 256 + col) = ll.v;
  } else if (blk < 2144) {                // Wc rows: [0,256)=Wq/16, [256,512)=Wk, [512,768)=Wv
    int q = blk - 2048;                   // 96 blocks
    int mat = q >> 5;
    int idx = (q & 31)*2048 + tid*8;      // 0..65535
    int o = idx >> 8, cc = idx & 255;
    const float* W = mat==0 ? Wq : (mat==1 ? Wk : Wv);
    float sc = (mat==0) ? 0.0625f : 1.0f;
    const float* p = W + (size_t)o*256 + cc;
    union { u16 s[8]; uint4 v; } hh, ll;
    #pragma unroll
    for (int i=0;i<8;++i){ float v = p[i]*sc; u16 h2 = f2bf(v); hh.s[i]=h2; ll.s[i]=f2bf(v - bf2f(h2)); }
    *(uint4*)(Wc + (size_t)(mat*256 + o)*512 + cc)       = hh.v;
    *(uint4*)(Wc + (size_t)(mat*256 + o)*512 + 256 + cc) = ll.v;
  } else if (blk < 2208) {                // bias-ext cols (64 blocks)
    int row = (blk - 2144)*256 + tid;     // b*4096 + s
    int s = row & (S-1);
    int bb = row >> 12;
    float b0 = beta[0], b1 = beta[1];
    int i24 = s % 24, i720 = s % 720;
    float t0 = (float)i24  * 0.26179938779914944f;    // 2pi/24
    float t1 = (float)i720 * 0.008726646259971648f;   // 2pi/720
    float c0 = cosf(t0), s0 = sinf(t0), c1 = cosf(t1), s1 = sinf(t1);
    float qv[4] = {b0*c0, b0*s0, b1*c1, b1*s1};   // beta folded on Q side
    float kv[4] = {c0, s0, c1, s1};
    u16* qp = Qb + (size_t)row*QSTR + 256;
    u16* kp = Kt + (size_t)(bb*128 + (s>>5))*KT_TILE + (s&31)*280 + 256;
    #pragma unroll
    for (int n=0;n<4;++n){
      u16 uh = f2bf(qv[n]); u16 ul = f2bf(qv[n]-bf2f(uh));
      u16 vh = f2bf(kv[n]); u16 vl = f2bf(kv[n]-bf2f(vh));
      // dot over triplet = uh*vh + uh*vl + ul*vh ~= u*v (drops ul*vl <= 2^-18)
      qp[n*3+0]=uh; qp[n*3+1]=uh; qp[n*3+2]=ul;
      kp[n*3+0]=vh; kp[n*3+1]=vl; kp[n*3+2]=vh;
    }
    #pragma unroll
    for (int c=12;c<16;++c){ qp[c]=0; kp[c]=0; }
  } else if (blk < 3232) {                // zero out (16.8 MB)
    float4* p = (float4*)(out + (size_t)(blk-2208)*4096);
    float4 z = {0.f,0.f,0.f,0.f};
    #pragma unroll
    for (int c=0;c<4;++c) p[tid + c*256] = z;
  } else {                                // zero Lacc (16384 f32)
    float4* p = (float4*)Lacc;
    float4 z = {0.f,0.f,0.f,0.f};
    #pragma unroll
    for (int c=0;c<16;++c) p[tid + c*256] = z;
  }
}

// ---------------- fused projection GEMM: C[16384x768] = xc . Wc^T, route Q/K/V ----------------
__global__ __launch_bounds__(256, 2) void msp_proj(
    const u16* __restrict__ xc, const u16* __restrict__ Wc,
    const float* __restrict__ bq, const float* __restrict__ bk, const float* __restrict__ bv,
    u16* __restrict__ Qb, u16* __restrict__ Kt, u16* __restrict__ Vt)
{
  __shared__ __align__(16) u16 smem[2][2][128][72];   // [buf][A/B][row][64+8pad] = 73728 B

  const int tid = threadIdx.x;
  const int w = tid >> 6, lane = tid & 63;
  const int l31 = lane & 31, h = lane >> 5;
  const int m0 = blockIdx.x * 128;
  const int nblk = blockIdx.y;
  const int n0 = nblk * 128, mat = nblk >> 1, cb = (nblk & 1) * 128;
  const int mh = (w & 1) * 64, nh = (w >> 1) * 64;

  const int srow = tid & 127;
  const int isB = tid >> 7;
  const u16* sgbase = isB ? (Wc + (size_t)(n0 + srow)*512) : (xc + (size_t)(m0 + srow)*512);

  { // prologue: chunk 0 -> buf 0
    u16* d = &smem[0][isB][srow][0];
    #pragma unroll
    for (int jj=0; jj<8; ++jj) *(uint4*)(d + jj*8) = *(const uint4*)(sgbase + jj*8);
  }

  f32x16 acc[2][2];
  #pragma unroll
  for (int a=0;a<2;++a)
    #pragma unroll
    for (int c=0;c<2;++c)
      #pragma unroll
      for (int i=0;i<16;++i) acc[a][c][i] = 0.f;

  for (int kc8 = 0; kc8 < 8; ++kc8) {
    __syncthreads();
    const int p = kc8 & 1;
    uint4 nxt[8];
    if (kc8 < 7) {
      const u16* g = sgbase + (kc8+1)*64;
      #pragma unroll
      for (int jj=0; jj<8; ++jj) nxt[jj] = *(const uint4*)(g + jj*8);
    }
    #pragma unroll
    for (int kf = 0; kf < 4; ++kf) {
      const int ko = kf*16 + h*8;
      bf16x8 a0 = *(const bf16x8*)&smem[p][0][mh + l31][ko];
      bf16x8 a1 = *(const bf16x8*)&smem[p][0][mh + 32 + l31][ko];
      bf16x8 b0 = *(const bf16x8*)&smem[p][1][nh + l31][ko];
      bf16x8 b1 = *(const bf16x8*)&smem[p][1][nh + 32 + l31][ko];
      acc[0][0] = __builtin_amdgcn_mfma_f32_32x32x16_bf16(a0, b0, acc[0][0], 0,0,0);
      acc[0][1] = __builtin_amdgcn_mfma_f32_32x32x16_bf16(a0, b1, acc[0][1], 0,0,0);
      acc[1][0] = __builtin_amdgcn_mfma_f32_32x32x16_bf16(a1, b0, acc[1][0], 0,0,0);
      acc[1][1] = __builtin_amdgcn_mfma_f32_32x32x16_bf16(a1, b1, acc[1][1], 0,0,0);
    }
    if (kc8 < 7) {
      u16* d = &smem[p^1][isB][srow][0];
      #pragma unroll
      for (int jj=0; jj<8; ++jj) *(uint4*)(d + jj*8) = nxt[jj];
    }
  }

  const float* bias = mat==0 ? bq : (mat==1 ? bk : bv);
  const float bsc = (mat==0) ? 0.0625f : 1.0f;   // W was pre-scaled; bias scaled here
  float bb_[2];
  #pragma unroll
  for (int ntl=0; ntl<2; ++ntl) bb_[ntl] = bias[cb + nh + ntl*32 + l31] * bsc;

  if (mat <= 1) {
    #pragma unroll
    for (int mt=0; mt<2; ++mt)
      #pragma unroll
      for (int ntl=0; ntl<2; ++ntl)
        #pragma unroll
        for (int r=0; r<16; ++r) {
          int gm = m0 + mh + mt*32 + (r&3) + 8*(r>>2) + 4*h;
          int col = cb + nh + ntl*32 + l31;
          u16 val = f2bf(acc[mt][ntl][r] + bb_[ntl]);
          if (mat == 0) {
            Qb[(size_t)gm*QSTR + col] = val;
          } else {
            int bb2 = gm >> 12, s = gm & (S-1);
            Kt[(size_t)(bb2*128 + (s>>5))*KT_TILE + (s&31)*280 + col] = val;
          }
        }
  } else {
    // V: transpose via LDS, store to Vt tiled [b][t32][e][40]
    u16* T = (u16*)smem;     // [128 e][136]
    #pragma unroll
    for (int mt=0; mt<2; ++mt)
      #pragma unroll
      for (int ntl=0; ntl<2; ++ntl)
        #pragma unroll
        for (int r=0; r<16; ++r) {
          int e_loc = nh + ntl*32 + l31;
          int m_loc = mh + mt*32 + (r&3) + 8*(r>>2) + 4*h;
          T[(size_t)e_loc*136 + m_loc] = f2bf(acc[mt][ntl][r] + bb_[ntl]);
        }
    __syncthreads();
    int e_loc = tid >> 1, shalf = (tid & 1)*64;
    int e = cb + e_loc;
    #pragma unroll
    for (int g2 = 0; g2 < 2; ++g2) {
      int gm = m0 + shalf + g2*32;
      int bb2 = gm >> 12, s = gm & (S-1);
      u16* dst = Vt + (size_t)(bb2*128 + (s>>5))*VT_TILE + (size_t)e*40;
      const u16* src = T + (size_t)e_loc*136 + shalf + g2*32;
      #pragma unroll
      for (int k2=0;k2<4;++k2) *(uint4*)(dst + k2*8) = *(const uint4*)(src + k2*8);
    }
  }
}

// ---------------- attention: BK=32, async dbuf, 2 blocks/CU, t-split partials via atomics ----
__global__ __launch_bounds__(256, 2) void msp_attn(
    const u16* __restrict__ Qb, const u16* __restrict__ Kt,
    const u16* __restrict__ Vt, float* __restrict__ out,
    float* __restrict__ Lacc)
{
  __shared__ __align__(16) unsigned char smem[77824];  // K dbuf 2x18432 | V dbuf 2x20480

  const int tid = threadIdx.x;
  const int w = tid >> 6, lane = tid & 63;
  const int l31 = lane & 31, h = lane >> 5;

  // XCD-swizzled decode over 512 blocks: 32 qt-blocks sharing (b,tq) land on one XCD
  const int xg = blockIdx.x;
  const int xcd = xg & 7, j = xg >> 3;
  const int c = xcd*2 + (j & 1);
  const int qt = j >> 1;
  const int b = c >> 2, tq = c & 3;
  const int q0 = qt * 128;
  const int qw = q0 + w*32;

  // Q fragments (B-operand): lane holds Q[qw+l31][16*s2 + 8h + j]
  bf16x8 qf[17];
  {
    const u16* qp = Qb + ((size_t)b*S + qw + l31)*QSTR + h*8;
    #pragma unroll
    for (int s2=0; s2<17; ++s2) qf[s2] = *(const bf16x8*)(qp + s2*16);
  }

  const int tIdx0 = b*128 + tq*32;

  f32x16 oacc[8];
  #pragma unroll
  for (int e=0;e<8;++e)
    #pragma unroll
    for (int i=0;i<16;++i) oacc[e][i] = 0.f;
  float l_acc = 0.f;

  { // prologue: tile 0 -> buffer 0
    const u16* kg = Kt + (size_t)tIdx0*KT_TILE;
    u16* kl = (u16*)smem;
    #pragma unroll
    for (int i = w; i < 18; i += 4) gl_lds16(kg + i*512 + lane*8, kl + i*512);
    const u16* vg = Vt + (size_t)tIdx0*VT_TILE;
    u16* vl = (u16*)(smem + 36864);
    #pragma unroll
    for (int i = w; i < 20; i += 4) gl_lds16(vg + i*512 + lane*8, vl + i*512);
  }

  for (int it = 0; it < 32; ++it) {
    __syncthreads();            // buf[it&1] staged; previous buf's readers drained
    const int p = it & 1;
    if (it < 31) {              // async-stage next tile into the other buffer
      const u16* kg = Kt + (size_t)(tIdx0 + it + 1)*KT_TILE;
      u16* kl = (u16*)(smem + (p^1)*18432);
      #pragma unroll
      for (int i = w; i < 18; i += 4) gl_lds16(kg + i*512 + lane*8, kl + i*512);
      const u16* vg = Vt + (size_t)(tIdx0 + it + 1)*VT_TILE;
      u16* vl = (u16*)(smem + 36864 + (p^1)*20480);
      #pragma unroll
      for (int i = w; i < 20; i += 4) gl_lds16(vg + i*512 + lane*8, vl + i*512);
    }

    // S^T = K Q^T (scale + periodic bias folded into the 272-dim), 2 chains
    const u16* Kp = (const u16*)(smem + p*18432) + (size_t)l31*280 + h*8;
    f32x16 sa, sb;
    #pragma unroll
    for (int i=0;i<16;++i){ sa[i] = 0.f; sb[i] = 0.f; }
    #pragma unroll
    for (int s2 = 0; s2 < 17; ++s2) {
      bf16x8 kf = *(const bf16x8*)(Kp + s2*16);
      if (s2 & 1) sb = __builtin_amdgcn_mfma_f32_32x32x16_bf16(kf, qf[s2], sb, 0,0,0);
      else        sa = __builtin_amdgcn_mfma_f32_32x32x16_bf16(kf, qf[s2], sa, 0,0,0);
    }
    f32x16 sc = sa + sb;

    // p = exp(s) (scores bounded ~|9|); build P^T B-frags via xor-32 exchange
    bf16x8 pf[2];
    #pragma unroll
    for (int s2 = 0; s2 < 2; ++s2) {
      float e0 = __expf(sc[8*s2+0]), e1 = __expf(sc[8*s2+1]);
      float e2 = __expf(sc[8*s2+2]), e3 = __expf(sc[8*s2+3]);
      float e4 = __expf(sc[8*s2+4]), e5 = __expf(sc[8*s2+5]);
      float e6 = __expf(sc[8*s2+6]), e7 = __expf(sc[8*s2+7]);
      int P0d0 = packbf(e0, e1), P0d1 = packbf(e2, e3);
      int P1d0 = packbf(e4, e5), P1d1 = packbf(e6, e7);
      // l sums the bf16-ROUNDED p so normalization cancels rounding bias
      l_acc += bfsum2(P0d0) + bfsum2(P0d1) + bfsum2(P1d0) + bfsum2(P1d1);
      int s0 = h ? P0d0 : P1d0;
      int s1 = h ? P0d1 : P1d1;
      int r0 = __shfl_xor(s0, 32, 64);
      int r1 = __shfl_xor(s1, 32, 64);
      union { int d[4]; bf16x8 v; } u;
      u.d[0] = h ? r0 : P0d0;
      u.d[1] = h ? r1 : P0d1;
      u.d[2] = h ? P1d0 : r0;
      u.d[3] = h ? P1d1 : r1;
      pf[s2] = u.v;
    }

    // O^T += V^T P^T
    const u16* Vp = (const u16*)(smem + 36864 + p*20480) + (size_t)l31*40 + h*8;
    #pragma unroll
    for (int et = 0; et < 8; ++et) {
      const u16* vb = Vp + et*32*40;
      oacc[et] = __builtin_amdgcn_mfma_f32_32x32x16_bf16(*(const bf16x8*)(vb),      pf[0], oacc[et], 0,0,0);
      oacc[et] = __builtin_amdgcn_mfma_f32_32x32x16_bf16(*(const bf16x8*)(vb + 16), pf[1], oacc[et], 0,0,0);
    }
  }

  // l: fold h-halves, one atomic per q-row
  float l_tot = l_acc + __shfl_xor(l_acc, 32, 64);
  if (h == 0) unsafeAtomicAdd(&Lacc[(size_t)b*S + qw + l31], l_tot);

  // transpose O^T -> O via LDS (4 rounds, one wave each), COALESCED fp32 atomics into out:
  // consecutive lanes -> consecutive dwords (R4's strided pattern caused 8x write amplification)
  float* Ofl = (float*)smem;    // [32 q][260]
  for (int rnd = 0; rnd < 4; ++rnd) {
    __syncthreads();
    if (w == rnd) {
      #pragma unroll
      for (int et=0; et<8; ++et)
        #pragma unroll
        for (int g=0; g<4; ++g) {
          float4 v4 = { oacc[et][4*g+0], oacc[et][4*g+1], oacc[et][4*g+2], oacc[et][4*g+3] };
          *(float4*)&Ofl[(size_t)l31*260 + et*32 + 8*g + 4*h] = v4;
        }
    }
    __syncthreads();
    float* obase = out + ((size_t)b*S + q0 + rnd*32)*D;
    #pragma unroll
    for (int q = 0; q < 32; ++q)
      unsafeAtomicAdd(obase + (size_t)q*D + tid, Ofl[(size_t)q*260 + tid]);
  }
}

// ---------------- normalize ----------------
__global__ __launch_bounds__(256) void msp_norm(float* __restrict__ out, const float* __restrict__ L) {
  int idx = blockIdx.x*256 + threadIdx.x;
  int row = idx >> 6, e0 = (idx & 63)*4;
  float inv = 1.0f / L[row];
  float4* p = (float4*)(out + (size_t)row*256 + e0);
  float4 v = *p;
  v.x *= inv; v.y *= inv; v.z *= inv; v.w *= inv;
  *p = v;
}

extern "C" void kernel_launch(void* const* d_in, const int* in_sizes, int n_in,
                              void* d_out, int out_size, void* d_ws, size_t ws_size,
                              hipStream_t stream) {
  const float* x    = (const float*)d_in[0];
  const float* Wq   = (const float*)d_in[1];
  const float* bq   = (const float*)d_in[2];
  const float* Wk   = (const float*)d_in[3];
  const float* bk   = (const float*)d_in[4];
  const float* Wv   = (const float*)d_in[5];
  const float* bv   = (const float*)d_in[6];
  const float* beta = (const float*)d_in[7];
  float* out = (float*)d_out;

  char* w = (char*)d_ws;
  u16* xc = (u16*)w;  w += (size_t)16384*512*2;     // 16.8 MB
  u16* Wc = (u16*)w;  w += (size_t)768*512*2;       // 0.79 MB
  u16* Qb = (u16*)w;  w += (size_t)16384*QSTR*2;    // 8.9 MB
  u16* Kt = (u16*)w;  w += (size_t)512*KT_TILE*2;   // 9.2 MB (Vt must follow: junk-tail reads)
  u16* Vt = (u16*)w;  w += (size_t)512*VT_TILE*2;   // 10.5 MB
  float* Lacc = (float*)w;                          // 64 KB

  msp_prep<<<3233, 256, 0, stream>>>(x, Wq, Wk, Wv, beta, xc, Wc, Qb, Kt, out, Lacc);
  msp_proj<<<dim3(128, 6), 256, 0, stream>>>(xc, Wc, bq, bk, bv, Qb, Kt, Vt);
  msp_attn<<<512, 256, 0, stream>>>(Qb, Kt, Vt, out, Lacc);
  msp_norm<<<4096, 256, 0, stream>>>(out, Lacc);
}